// Round 4
// baseline (328.702 us; speedup 1.0000x reference)
//
#include <hip/hip_runtime.h>
#include <hip/hip_bf16.h>
#include <math.h>

#define N_  128
#define D_  512
#define L_  512
#define K_  512
#define KH_ 256       // mirror symmetry: out[..,k] == out[..,511-k]
#define M_  (N_*D_)   // 65536

typedef __bf16 bf16x8 __attribute__((ext_vector_type(8)));
typedef float  f32x4  __attribute__((ext_vector_type(4)));
typedef unsigned short ushort_t;

// ---------------------------------------------------------------------------
// Kernel 1: bf16 DFT basis for k = 0..255 ONLY (exact mirror symmetry:
// ang(l,511-k) = 2*pi*l - ang(l,k) for integer l => cos equal, sin negated,
// so |X[...,511-k]| == |X[...,k]| exactly). Plus separable window tables:
// P=a*e, Q=-(1-a)*e, e=exp(sigma/511), C[l]=cos(2*pi*l/511).
// ---------------------------------------------------------------------------
__global__ void basis_kernel(const float* __restrict__ a,
                             const float* __restrict__ sigma,
                             ushort_t* __restrict__ Bc,
                             ushort_t* __restrict__ Bs,
                             float* __restrict__ P,
                             float* __restrict__ Q,
                             float* __restrict__ C) {
    int idx = blockIdx.x * 256 + threadIdx.x;   // 0 .. 256*512-1
    int r = idx >> 9;    // k (0..255)
    int c = idx & 511;   // l
    unsigned m = (unsigned)(r * c) % 511u;      // exact periodic reduction
    const float w0 = 6.283185307179586f / 511.0f;
    float sn, cs;
    sincosf((float)m * w0, &sn, &cs);
    __hip_bfloat16 bc = __float2bfloat16(cs);
    __hip_bfloat16 bs = __float2bfloat16(sn);
    ushort_t uc, us;
    __builtin_memcpy(&uc, &bc, 2);
    __builtin_memcpy(&us, &bs, 2);
    Bc[idx] = uc;
    Bs[idx] = us;
    if (idx < 512) {
        float e = expf(sigma[idx] * (1.0f / 511.0f));
        P[idx] = a[idx] * e;
        Q[idx] = -(1.0f - a[idx]) * e;
        C[idx] = cosf((float)idx * w0);
    }
}

static __device__ __forceinline__ unsigned pack_bf16x2(float lo, float hi) {
    __hip_bfloat162 h = __float22bfloat162_rn(make_float2(lo, hi));
    unsigned u;
    __builtin_memcpy(&u, &h, 4);
    return u;   // lo in low 16 bits -> memory order [lo, hi]
}

// ---------------------------------------------------------------------------
// Kernel 2: barrier-free direct-register dual-MFMA GEMM.
//  - NO LDS, NO __syncthreads, NO vmcnt(0) drains: every wave independent.
//  - Each block = one 64-row M-panel; its 4 waves take the 4 N-column groups
//    (same x chunk read 4x -> L1 hits within the CU).
//  - A frags built in regs: 2x float4 from x, window fma (P+Q*C), bf16 pack.
//    Window recompute rides the otherwise-idle VALU pipe.
//  - B frags: one dwordx4 per frag straight from L2-resident Bc/Bs (512 KB).
//  - Epilogue: magnitude + exact mirror write (col and 511-col).
// Frag layouts (verified lineage m89/m91 + rounds 1-3):
//   A: lane(ml,quad) -> row=ml(+16*mi), k=quad*8+j
//   B: lane(ml,quad) -> col=ml(+16*ni), k=quad*8+j
//   C/D: col=ml, row=quad*4+r(+16*mi)
// ---------------------------------------------------------------------------
__global__ __launch_bounds__(256, 2)
void dft_gemm6(const float* __restrict__ x,
               const ushort_t* __restrict__ Bc,
               const ushort_t* __restrict__ Bs,
               const float* __restrict__ P,
               const float* __restrict__ Q,
               const float* __restrict__ C,
               float* __restrict__ out) {
    const int tid  = threadIdx.x;
    const int w    = tid >> 6;      // 0..3: N-column group of this wave
    const int lane = tid & 63;
    const int ml   = lane & 15;
    const int quad = lane >> 4;

    const int m0 = blockIdx.x * 64;     // 1024 blocks = M/64 panels
    const int n0 = w * 64;              // half-K column base (0..192)
    const int d0 = m0 & (D_ - 1);       // 64-row panel never crosses D bound

    // per-frag window row constants (L1-resident tables)
    float p[4], q[4];
#pragma unroll
    for (int mi = 0; mi < 4; ++mi) {
        p[mi] = P[d0 + mi * 16 + ml];
        q[mi] = Q[d0 + mi * 16 + ml];
    }

    const float*    xb  = x  + (size_t)(m0 + ml) * L_ + quad * 8;
    const ushort_t* bcb = Bc + (size_t)(n0 + ml) * L_ + quad * 8;
    const ushort_t* bsb = Bs + (size_t)(n0 + ml) * L_ + quad * 8;
    const float*    Cb  = C  + quad * 8;

    f32x4 acc_c[4][4], acc_s[4][4];
    const f32x4 zero = {0.f, 0.f, 0.f, 0.f};
#pragma unroll
    for (int mi = 0; mi < 4; ++mi)
#pragma unroll
        for (int ni = 0; ni < 4; ++ni) { acc_c[mi][ni] = zero; acc_s[mi][ni] = zero; }

    for (int kk = 0; kk < L_; kk += 32) {
        // window cosine chunk for this k-tile (2 KB table, L1)
        float4 c0 = *(const float4*)(Cb + kk);
        float4 c1 = *(const float4*)(Cb + kk + 4);

        // B frags straight from L2 (16B per frag per lane)
        bf16x8 bcf[4], bsf[4];
#pragma unroll
        for (int ni = 0; ni < 4; ++ni) {
            bcf[ni] = *(const bf16x8*)(bcb + ni * (16 * L_) + kk);
            bsf[ni] = *(const bf16x8*)(bsb + ni * (16 * L_) + kk);
        }

        // A frags: load fp32 x, apply window, pack to bf16 in regs
        bf16x8 af[4];
#pragma unroll
        for (int mi = 0; mi < 4; ++mi) {
            float4 v0 = *(const float4*)(xb + mi * (16 * L_) + kk);
            float4 v1 = *(const float4*)(xb + mi * (16 * L_) + kk + 4);
            float w0 = fmaf(q[mi], c0.x, p[mi]);
            float w1 = fmaf(q[mi], c0.y, p[mi]);
            float w2 = fmaf(q[mi], c0.z, p[mi]);
            float w3 = fmaf(q[mi], c0.w, p[mi]);
            float w4 = fmaf(q[mi], c1.x, p[mi]);
            float w5 = fmaf(q[mi], c1.y, p[mi]);
            float w6 = fmaf(q[mi], c1.z, p[mi]);
            float w7 = fmaf(q[mi], c1.w, p[mi]);
            int4 pk;
            pk.x = (int)pack_bf16x2(v0.x * w0, v0.y * w1);
            pk.y = (int)pack_bf16x2(v0.z * w2, v0.w * w3);
            pk.z = (int)pack_bf16x2(v1.x * w4, v1.y * w5);
            pk.w = (int)pack_bf16x2(v1.z * w6, v1.w * w7);
            __builtin_memcpy(&af[mi], &pk, 16);
        }

        // 32 MFMA (dual accumulator)
#pragma unroll
        for (int mi = 0; mi < 4; ++mi)
#pragma unroll
            for (int ni = 0; ni < 4; ++ni) {
                acc_c[mi][ni] = __builtin_amdgcn_mfma_f32_16x16x32_bf16(
                    af[mi], bcf[ni], acc_c[mi][ni], 0, 0, 0);
                acc_s[mi][ni] = __builtin_amdgcn_mfma_f32_16x16x32_bf16(
                    af[mi], bsf[ni], acc_s[mi][ni], 0, 0, 0);
            }
    }

    // epilogue: magnitude + exact mirror write
#pragma unroll
    for (int mi = 0; mi < 4; ++mi)
#pragma unroll
        for (int ni = 0; ni < 4; ++ni) {
#pragma unroll
            for (int r = 0; r < 4; ++r) {
                float cv = acc_c[mi][ni][r];
                float sv = acc_s[mi][ni][r];
                int row = m0 + mi * 16 + quad * 4 + r;
                int col = n0 + ni * 16 + ml;
                float v = sqrtf(cv * cv + sv * sv);
                out[(size_t)row * K_ + col] = v;
                out[(size_t)row * K_ + (K_ - 1 - col)] = v;
            }
        }
}

extern "C" void kernel_launch(void* const* d_in, const int* in_sizes, int n_in,
                              void* d_out, int out_size, void* d_ws, size_t ws_size,
                              hipStream_t stream) {
    (void)in_sizes; (void)n_in; (void)out_size; (void)ws_size;
    const float* x     = (const float*)d_in[0];
    const float* a     = (const float*)d_in[1];
    const float* sigma = (const float*)d_in[2];
    float* out = (float*)d_out;

    // ws: Bc (256KB) | Bs (256KB) | P (2KB) | Q (2KB) | C (2KB)
    ushort_t* Bc = (ushort_t*)d_ws;
    ushort_t* Bs = Bc + KH_ * 512;
    float*    P  = (float*)(Bs + KH_ * 512);
    float*    Q  = P + 512;
    float*    C  = Q + 512;

    basis_kernel<<<dim3(512), dim3(256), 0, stream>>>(a, sigma, Bc, Bs, P, Q, C);
    dft_gemm6<<<dim3(1024), dim3(256), 0, stream>>>(x, Bc, Bs, P, Q, C, out);
}

// Round 5
// 281.771 us; speedup vs baseline: 1.1666x; 1.1666x over previous
//
#include <hip/hip_runtime.h>
#include <hip/hip_bf16.h>
#include <math.h>

#define N_  128
#define D_  512
#define L_  512
#define K_  512
#define KH_ 256       // mirror symmetry: out[..,k] == out[..,511-k]
#define M_  (N_*D_)   // 65536

typedef __bf16 bf16x8 __attribute__((ext_vector_type(8)));
typedef float  f32x4  __attribute__((ext_vector_type(4)));
typedef unsigned short ushort_t;

// ---------------------------------------------------------------------------
// Kernel 1: bf16 DFT basis for k = 0..255 (exact mirror symmetry), stored in
// FRAGMENT-MAJOR layout: tile (nb16 = n/16, kt = l/32) is 64 lanes x 16B
// contiguous (1 KB), lane = quad*16 + ml holds cols n=nb16*16+ml,
// k = kt*32 + quad*8 + j. GEMM B-frag load = one coalesced dwordx4/lane.
// Window tables: P=a*e, Q=-(1-a)*e, e=exp(sigma/511), C[l]=cos(2*pi*l/511).
// ---------------------------------------------------------------------------
__global__ void basis_kernel(const float* __restrict__ a,
                             const float* __restrict__ sigma,
                             ushort_t* __restrict__ Bc,
                             ushort_t* __restrict__ Bs,
                             float* __restrict__ P,
                             float* __restrict__ Q,
                             float* __restrict__ C) {
    int idx = blockIdx.x * 256 + threadIdx.x;   // 0 .. 256*512-1
    int r = idx >> 9;    // n (0..255)
    int c = idx & 511;   // l (0..511)
    unsigned m = (unsigned)(r * c) % 511u;      // exact periodic reduction
    const float w0 = 6.283185307179586f / 511.0f;
    float sn, cs;
    sincosf((float)m * w0, &sn, &cs);
    __hip_bfloat16 bc = __float2bfloat16(cs);
    __hip_bfloat16 bs = __float2bfloat16(sn);
    ushort_t uc, us;
    __builtin_memcpy(&uc, &bc, 2);
    __builtin_memcpy(&us, &bs, 2);
    // fragment-major position
    int nb16 = r >> 4, ml = r & 15;
    int kt = c >> 5, quad = (c >> 3) & 3, j = c & 7;
    size_t pos = ((size_t)((nb16 * 16 + kt) * 64 + quad * 16 + ml)) * 8 + j;
    Bc[pos] = uc;
    Bs[pos] = us;
    if (idx < 512) {
        float e = expf(sigma[idx] * (1.0f / 511.0f));
        P[idx] = a[idx] * e;
        Q[idx] = -(1.0f - a[idx]) * e;
        C[idx] = cosf((float)idx * w0);
    }
}

static __device__ __forceinline__ unsigned pack_bf16x2(float lo, float hi) {
    __hip_bfloat162 h = __float22bfloat162_rn(make_float2(lo, hi));
    unsigned u;
    __builtin_memcpy(&u, &h, 4);
    return u;   // lo in low 16 bits -> memory order [lo, hi]
}

// ---------------------------------------------------------------------------
// Kernel 2: barrier-free GEMM, coalescing fixed.
//  - NO __syncthreads. Each of the 4 waves owns a 64x64 dual tile (n-group w).
//  - B frags: direct coalesced dwordx4 from fragment-major Bc/Bs (L1/L2-hot;
//    loaded per-ni inside the MFMA loop so only 2 live at once).
//  - A: coalesced fp32 x loads (thread rt=lane>>2 rows, ct=lane&3 k-chunks)
//    -> window fma + bf16 pack in regs -> wave-PRIVATE LDS transit with the
//    verified XOR involution -> ds_read_b128 frags. Same-wave DS ordering
//    (lgkmcnt) is the only sync. Double-buffered, compile-time buffer names.
//  - T14 split: x loads for tile t+1 issued before tile t's MFMA phase.
//  - T5: setprio(1) around pure-MFMA clusters (independent-wave regime).
// ---------------------------------------------------------------------------
__global__ __launch_bounds__(256, 2)
void dft_gemm7(const float* __restrict__ x,
               const ushort_t* __restrict__ Bc,
               const ushort_t* __restrict__ Bs,
               const float* __restrict__ P,
               const float* __restrict__ Q,
               const float* __restrict__ C,
               float* __restrict__ out) {
    // [wave][2 buf][64 rows][32 k] bf16 = 4 * 8 KB = 32 KB
    __shared__ ushort_t sA[4 * 2 * 64 * 32];

    const int tid  = threadIdx.x;
    const int w    = tid >> 6;          // n-group 0..3
    const int lane = tid & 63;
    const int ml   = lane & 15;
    const int quad = lane >> 4;

    const int m0 = blockIdx.x * 64;     // 1024 blocks
    const int d0 = m0 & (D_ - 1);       // panel never crosses D boundary
    const int n0 = w * 64;

    ushort_t* A0 = sA + w * 4096;       // this wave's buffer 0 (4 KB)
    ushort_t* A1 = A0 + 2048;           // buffer 1

    // ---- staging mapping: thread (rt, ct); 4 rowblocks of 16 rows ----
    const int rt = lane >> 2;           // 0..15
    const int ct = lane & 3;            // 8-elem k-chunk

    float pr[4], qr[4];
#pragma unroll
    for (int rb = 0; rb < 4; ++rb) {
        pr[rb] = P[d0 + rb * 16 + rt];
        qr[rb] = Q[d0 + rb * 16 + rt];
    }
    const float* xb = x + (size_t)(m0 + rt) * L_ + ct * 8;
    const float* Cb = C + ct * 8;

    int wOff[4];                        // swizzled ds_write offsets
#pragma unroll
    for (int rb = 0; rb < 4; ++rb) {
        int row = rb * 16 + rt;
        int pc  = ct ^ ((row >> 1) & 3);
        wOff[rb] = row * 32 + pc * 8;
    }
    int aOff[4];                        // swizzled frag-read offsets
#pragma unroll
    for (int mi = 0; mi < 4; ++mi) {
        int ar = mi * 16 + ml;
        int pc = quad ^ ((ar >> 1) & 3);
        aOff[mi] = ar * 32 + pc * 8;
    }

    f32x4 acc_c[4][4], acc_s[4][4];
    const f32x4 zero = {0.f, 0.f, 0.f, 0.f};
#pragma unroll
    for (int mi = 0; mi < 4; ++mi)
#pragma unroll
        for (int ni = 0; ni < 4; ++ni) { acc_c[mi][ni] = zero; acc_s[mi][ni] = zero; }

    float4 xv[8];   // one k-tile of x in flight (8 x float4, indices static)

    auto xload = [&](int kk) {
#pragma unroll
        for (int rb = 0; rb < 4; ++rb) {
            xv[2 * rb]     = *(const float4*)(xb + (size_t)rb * 16 * L_ + kk);
            xv[2 * rb + 1] = *(const float4*)(xb + (size_t)rb * 16 * L_ + kk + 4);
        }
    };

    auto packwrite = [&](int kk, ushort_t* Abuf) {
        float4 c0 = *(const float4*)(Cb + kk);
        float4 c1 = *(const float4*)(Cb + kk + 4);
#pragma unroll
        for (int rb = 0; rb < 4; ++rb) {
            float p = pr[rb], q = qr[rb];
            float w0v = fmaf(q, c0.x, p), w1v = fmaf(q, c0.y, p);
            float w2v = fmaf(q, c0.z, p), w3v = fmaf(q, c0.w, p);
            float w4v = fmaf(q, c1.x, p), w5v = fmaf(q, c1.y, p);
            float w6v = fmaf(q, c1.z, p), w7v = fmaf(q, c1.w, p);
            float4 v0 = xv[2 * rb], v1 = xv[2 * rb + 1];
            int4 pk;
            pk.x = (int)pack_bf16x2(v0.x * w0v, v0.y * w1v);
            pk.y = (int)pack_bf16x2(v0.z * w2v, v0.w * w3v);
            pk.z = (int)pack_bf16x2(v1.x * w4v, v1.y * w5v);
            pk.w = (int)pack_bf16x2(v1.z * w6v, v1.w * w7v);
            *(int4*)(Abuf + wOff[rb]) = pk;
        }
    };

    auto mfma_tile = [&](const ushort_t* Abuf, int kt) {
        bf16x8 af[4];
#pragma unroll
        for (int mi = 0; mi < 4; ++mi)
            af[mi] = *(const bf16x8*)(Abuf + aOff[mi]);
#pragma unroll
        for (int ni = 0; ni < 4; ++ni) {
            const size_t tb = (((size_t)(w * 4 + ni) * 16 + kt) * 64 + lane) * 8;
            bf16x8 bcf = *(const bf16x8*)(Bc + tb);
            bf16x8 bsf = *(const bf16x8*)(Bs + tb);
            __builtin_amdgcn_s_setprio(1);
#pragma unroll
            for (int mi = 0; mi < 4; ++mi) {
                acc_c[mi][ni] = __builtin_amdgcn_mfma_f32_16x16x32_bf16(
                    af[mi], bcf, acc_c[mi][ni], 0, 0, 0);
                acc_s[mi][ni] = __builtin_amdgcn_mfma_f32_16x16x32_bf16(
                    af[mi], bsf, acc_s[mi][ni], 0, 0, 0);
            }
            __builtin_amdgcn_s_setprio(0);
        }
    };

    // ---- pipeline: 16 k-tiles, 2x unrolled, fixed buffer names ----
    xload(0);
    packwrite(0, A0);
#pragma unroll 1
    for (int t = 0; t < 14; t += 2) {
        xload((t + 1) * 32);            // issue early (T14)
        mfma_tile(A0, t);
        packwrite((t + 1) * 32, A1);    // write late
        xload((t + 2) * 32);
        mfma_tile(A1, t + 1);
        packwrite((t + 2) * 32, A0);
    }
    xload(15 * 32);
    mfma_tile(A0, 14);
    packwrite(15 * 32, A1);
    mfma_tile(A1, 15);

    // ---- epilogue: magnitude + exact mirror write ----
#pragma unroll
    for (int mi = 0; mi < 4; ++mi)
#pragma unroll
        for (int ni = 0; ni < 4; ++ni) {
#pragma unroll
            for (int r = 0; r < 4; ++r) {
                float cv = acc_c[mi][ni][r];
                float sv = acc_s[mi][ni][r];
                int row = m0 + mi * 16 + quad * 4 + r;
                int col = n0 + ni * 16 + ml;
                float v = sqrtf(cv * cv + sv * sv);
                out[(size_t)row * K_ + col] = v;
                out[(size_t)row * K_ + (K_ - 1 - col)] = v;
            }
        }
}

extern "C" void kernel_launch(void* const* d_in, const int* in_sizes, int n_in,
                              void* d_out, int out_size, void* d_ws, size_t ws_size,
                              hipStream_t stream) {
    (void)in_sizes; (void)n_in; (void)out_size; (void)ws_size;
    const float* x     = (const float*)d_in[0];
    const float* a     = (const float*)d_in[1];
    const float* sigma = (const float*)d_in[2];
    float* out = (float*)d_out;

    // ws: Bc (256KB) | Bs (256KB) | P (2KB) | Q (2KB) | C (2KB)
    ushort_t* Bc = (ushort_t*)d_ws;
    ushort_t* Bs = Bc + KH_ * 512;
    float*    P  = (float*)(Bs + KH_ * 512);
    float*    Q  = P + 512;
    float*    C  = Q + 512;

    basis_kernel<<<dim3(512), dim3(256), 0, stream>>>(a, sigma, Bc, Bs, P, Q, C);
    dft_gemm7<<<dim3(1024), dim3(256), 0, stream>>>(x, Bc, Bs, P, Q, C, out);
}